// Round 1
// baseline (120.122 us; speedup 1.0000x reference)
//
#include <hip/hip_runtime.h>
#include <hip/hip_bf16.h>
#include <math.h>

// Self_Attention_Local R6: fused bf16-MFMA attention, no atomics.
//   convertW: Wq/Wk/Wv -> Wp[x][h][i][k] bf16, Wout -> Wout_pt[h][col][i] bf16
//   attn4:    block = (patch-group of 4, head). QKV -> QT/KT (transposed) +
//             VS (natural, bank-swizzled). Stats via pass-1: recompute score
//             MFMAs accumulating sum/sumsq in-register (QN/KN zones deleted,
//             LDS 40->32KB, 5 blocks/CU). Pass-2 softmax+PV with conflict-free
//             P swizzle (key = row>>2 so all 4 quads hit distinct bank octets).
//             Band 7 of pass-1 is reused as pass-2's first band.
//   reduce8:  out[orow(pat,p)][col] = sum_h part[h][pat*8+p][col]  (+ permute)

typedef short bfrag __attribute__((ext_vector_type(8)));   // 8 bf16 = 4 VGPRs
typedef float f32x4 __attribute__((ext_vector_type(4)));

static __device__ __forceinline__ short f2bf(float x) {
    __hip_bfloat16 h = __float2bfloat16(x);
    return __builtin_bit_cast(short, h);
}
static __device__ __forceinline__ bfrag bzero() {
    bfrag z;
    #pragma unroll
    for (int j = 0; j < 8; ++j) z[j] = 0;
    return z;
}

// ---------------- convertW: 128 blocks ----------------
// blocks 0..95:  (x, h, k-quarter): Wp[x][h][i][k] = Wx[k][i*8+h]
// blocks 96..127:(h, col-quarter):  Wout_pt[h][col][i] = Wout[i*8+h][col]
__global__ __launch_bounds__(256) void convertW(
    const float* __restrict__ Wq, const float* __restrict__ Wk,
    const float* __restrict__ Wv, const float* __restrict__ Wout,
    short* __restrict__ Wp, short* __restrict__ Wout_pt)
{
    __shared__ short lt[128 * 33];          // union: [32][129] or [128][33]
    const int b = blockIdx.x, t = threadIdx.x;
    if (b < 96) {
        const int x = b >> 5, h = (b >> 2) & 7, k0 = (b & 3) * 32;
        const float* W = (x == 0) ? Wq : (x == 1) ? Wk : Wv;
        #pragma unroll 4
        for (int rr = 0; rr < 16; ++rr) {
            const int k = rr * 2 + (t >> 7);          // 0..31
            const int i = t & 127;
            lt[k * 129 + i] = f2bf(W[(k0 + k) * 1024 + i * 8 + h]);
        }
        __syncthreads();
        short* dst = Wp + (x * 8 + h) * 16384;
        #pragma unroll
        for (int pp = 0; pp < 4; ++pp) {
            const int i  = pp * 32 + (t >> 3);
            const int kk = (t & 7) * 4;
            short4 v;
            v.x = lt[(kk + 0) * 129 + i]; v.y = lt[(kk + 1) * 129 + i];
            v.z = lt[(kk + 2) * 129 + i]; v.w = lt[(kk + 3) * 129 + i];
            *(short4*)&dst[i * 128 + k0 + kk] = v;
        }
    } else {
        const int b2 = b - 96, h = b2 >> 2, c0 = (b2 & 3) * 32;
        #pragma unroll 4
        for (int rr = 0; rr < 16; ++rr) {
            const int i = rr * 8 + (t >> 5);
            const int c = t & 31;
            lt[i * 33 + c] = f2bf(Wout[(i * 8 + h) * 128 + c0 + c]);
        }
        __syncthreads();
        short* dst = Wout_pt + h * 16384;
        #pragma unroll
        for (int pp = 0; pp < 4; ++pp) {
            const int c  = pp * 8 + (t >> 5);
            const int i0 = (t & 31) * 4;
            short4 v;
            v.x = lt[(i0 + 0) * 33 + c]; v.y = lt[(i0 + 1) * 33 + c];
            v.z = lt[(i0 + 2) * 33 + c]; v.w = lt[(i0 + 3) * 33 + c];
            *(short4*)&dst[(c0 + c) * 128 + i0] = v;
        }
    }
}

// ---------------- attn4 ----------------
// LDS zones (shorts), 32 KB total:
//   QT [0..4095]      Qt[pl][i][p]   (persists through pass-2 prefetch)
//   KT [4096..8191]   Kt[pl][j][p]   (dead after bs hoist -> P bufs)
//   VS [8192..12287]  V natural, bank-swizzled (dead after av hoist -> P bufs)
//   CTX[12288..16383] ctx [pl][p][i]
#define QT   0
#define KT   4096
#define VS   8192
#define CTXo 12288

__global__ __launch_bounds__(256, 5) void attn4(
    const float* __restrict__ emb,      // [4096][128] fp32
    const short* __restrict__ Wp,       // [3][8][128 i][128 k]
    const short* __restrict__ Wout_pt,  // [8][128 col][128 i]
    float* __restrict__ part)           // [8][4096][128] fp32 partials
{
    __shared__ short lds[16384];        // 32 KB
    const int bid = blockIdx.x;         // 0..1023
    const int pg  = bid >> 3;           // patch group of 4
    const int h   = bid & 7;            // head
    const int t   = threadIdx.x;
    const int w    = t >> 6;            // wave 0..3 (owns patch pl = w)
    const int lane = t & 63;
    const int m16  = lane & 15;
    const int quad = lane >> 4;
    const int q8   = quad * 8;

    // ================= QKV: (32x128) @ W_h (128x128) x3 =================
    {
        bfrag a[2][4];
        #pragma unroll
        for (int tm = 0; tm < 2; ++tm)
            #pragma unroll
            for (int ks = 0; ks < 4; ++ks) {
                const float* er = emb + (size_t)(pg*32 + tm*16 + m16) * 128 + ks*32 + q8;
                const float4 x0 = *(const float4*)er;
                const float4 x1 = *(const float4*)(er + 4);
                bfrag f;
                f[0]=f2bf(x0.x); f[1]=f2bf(x0.y); f[2]=f2bf(x0.z); f[3]=f2bf(x0.w);
                f[4]=f2bf(x1.x); f[5]=f2bf(x1.y); f[6]=f2bf(x1.z); f[7]=f2bf(x1.w);
                a[tm][ks] = f;
            }

        #pragma unroll
        for (int tt = 0; tt < 6; ++tt) {
            const int nt = w * 6 + tt;            // 0..23 = {q,k,v} x 8 i-tiles
            const int x  = nt >> 3;
            const int i0 = (nt & 7) * 16;
            const short* Wb = Wp + ((x*8 + h)*128 + i0 + m16) * 128;
            bfrag bb[4];
            #pragma unroll
            for (int ks = 0; ks < 4; ++ks)
                bb[ks] = *(const bfrag*)&Wb[ks*32 + q8];
            f32x4 c0 = {0.f,0.f,0.f,0.f}, c1 = {0.f,0.f,0.f,0.f};
            #pragma unroll
            for (int ks = 0; ks < 4; ++ks) {
                c0 = __builtin_amdgcn_mfma_f32_16x16x32_bf16(a[0][ks], bb[ks], c0, 0,0,0);
                c1 = __builtin_amdgcn_mfma_f32_16x16x32_bf16(a[1][ks], bb[ks], c1, 0,0,0);
            }
            #pragma unroll
            for (int tm = 0; tm < 2; ++tm) {
                const f32x4 cc = tm ? c1 : c0;
                const int mrow0 = tm*16 + quad*4;     // 4 consecutive tokens
                const int pl = mrow0 >> 3;            // local patch
                const int p0 = mrow0 & 7;             // 0 or 4
                const int col = i0 + m16;
                if (x == 0) {
                    short4 v;
                    v.x = f2bf(cc[0]); v.y = f2bf(cc[1]);
                    v.z = f2bf(cc[2]); v.w = f2bf(cc[3]);
                    *(short4*)&lds[QT + pl*1024 + col*8 + p0] = v;   // Qt[i][p]
                } else if (x == 1) {
                    short4 v;
                    v.x = f2bf(cc[0]); v.y = f2bf(cc[1]);
                    v.z = f2bf(cc[2]); v.w = f2bf(cc[3]);
                    *(short4*)&lds[KT + pl*1024 + col*8 + p0] = v;   // Kt[j][p]
                } else {
                    // Vs[p][j], column-group swizzled: key distinguishes the 4
                    // (pl,p0) combos a quad-set writes -> conflict-free.
                    const int g = (((nt & 7) ^ (((pl & 1) << 1) | (p0 >> 2))) << 4);
                    #pragma unroll
                    for (int r = 0; r < 4; ++r)
                        lds[VS + pl*1024 + (p0 + r)*128 + g + m16] = f2bf(cc[r]);
                }
            }
        }
    }
    __syncthreads();

    // ===== hoist K-transposed fragments (KT dies after this) ============
    bfrag bs[8];
    #pragma unroll
    for (int nt = 0; nt < 8; ++nt)
        bs[nt] = (quad == 0) ? *(const bfrag*)&lds[KT + w*1024 + (nt*16 + m16)*8] : bzero();

    // ===== pass-1: score MFMAs, accumulate sum/sumsq in-register ========
    // Band 7's scores stay in c[] and seed pass-2.
    f32x4 c[8];
    float ssum = 0.f, ssq = 0.f;
    {
        bfrag am = (quad == 0) ? *(const bfrag*)&lds[QT + w*1024 + m16*8] : bzero();
        #pragma unroll 1
        for (int mb = 0; mb < 8; ++mb) {
            bfrag amn = am;
            if (mb < 7)
                amn = (quad == 0)
                    ? *(const bfrag*)&lds[QT + w*1024 + ((mb+1)*16 + m16)*8] : bzero();
            #pragma unroll
            for (int nt = 0; nt < 8; ++nt) {
                f32x4 z = {0.f,0.f,0.f,0.f};
                c[nt] = __builtin_amdgcn_mfma_f32_16x16x32_bf16(am, bs[nt], z, 0,0,0);
            }
            #pragma unroll
            for (int nt = 0; nt < 8; ++nt)
                #pragma unroll
                for (int r = 0; r < 4; ++r) {
                    ssum += c[nt][r];
                    ssq   = fmaf(c[nt][r], c[nt][r], ssq);
                }
            am = amn;
        }
    }
    #pragma unroll
    for (int off = 1; off <= 32; off <<= 1) {
        ssum += __shfl_xor(ssum, off);
        ssq  += __shfl_xor(ssq,  off);
    }
    const float mean  = ssum * (1.f / 16384.f);
    const float var   = ssq  * (1.f / 16384.f) - mean * mean;
    const float rs2   = rsqrtf(var + 1e-5f) * 1.44269504f;   // fold log2(e)
    const float nbias = -mean * rs2;

    // ===== hoist V fragments + ones row (VS dies after this) ============
    bfrag av[4];
    #pragma unroll
    for (int ks = 0; ks < 4; ++ks) {
        if (m16 < 8) {
            const int g = (((2*ks + (quad >> 1)) ^ (((w & 1) << 1) | (m16 >> 2))) << 4);
            av[ks] = *(const bfrag*)&lds[VS + w*1024 + m16*128 + g + (quad & 1)*8];
        } else if (m16 == 8) {                 // ones ROW -> C[8][i] = rowsum_i
            bfrag o;
            #pragma unroll
            for (int j = 0; j < 8; ++j) o[j] = (short)0x3F80;
            av[ks] = o;
        } else
            av[ks] = bzero();
    }
    __syncthreads();   // all waves done with KT/VS -> safe to overlay P bufs

    // ===== pass-2: 8 bands; P conflict-free-swizzled; manual pipeline ====
    // P addr(i,j) = i*128 + (((j>>4) ^ (i>>2))<<4) + (j&15)
    //   write: i = quad*4+r  -> key = quad (distinct mod 4 across quads)
    //   read:  i = m16       -> key = m16>>2 (distinct mod 4 across lane groups)
    short* ps = &lds[KT + w*2048];             // 16 x 128 shorts per wave
    #pragma unroll 1
    for (int it = 0; it < 8; ++it) {
        const int mb = (it + 7) & 7;           // 7,0,1,...,6
        // exp + swizzled P write (rows quad*4+r, col nt*16+m16)
        #pragma unroll
        for (int nt = 0; nt < 8; ++nt)
            #pragma unroll
            for (int r = 0; r < 4; ++r) {
                const int row = quad*4 + r;
                ps[row*128 + ((nt ^ quad) << 4) + m16] =
                    f2bf(__builtin_amdgcn_exp2f(fmaf(c[nt][r], rs2, nbias)));
            }
        // next band's scores issue between P-write and PV-read (latency cover)
        if (it < 7) {
            const bfrag am2 = (quad == 0)
                ? *(const bfrag*)&lds[QT + w*1024 + (it*16 + m16)*8] : bzero();
            #pragma unroll
            for (int nt = 0; nt < 8; ++nt) {
                f32x4 z = {0.f,0.f,0.f,0.f};
                c[nt] = __builtin_amdgcn_mfma_f32_16x16x32_bf16(am2, bs[nt], z, 0,0,0);
            }
        }
        // PV: C[p][i16] = sum_j V[p][j] * P[i][j]   (B-frag = P rows, b128)
        f32x4 cc = {0.f,0.f,0.f,0.f};
        #pragma unroll
        for (int ks = 0; ks < 4; ++ks) {
            const bfrag bp = *(const bfrag*)
                &ps[m16*128 + (((2*ks + (quad >> 1)) ^ (m16 >> 2)) << 4) + (quad & 1)*8];
            cc = __builtin_amdgcn_mfma_f32_16x16x32_bf16(av[ks], bp, cc, 0,0,0);
        }
        const float s  = __shfl(cc[0], 32 + m16);   // C[8][i] from quad-2 lanes
        const float is = 1.0f / s;
        if (quad < 2) {
            #pragma unroll
            for (int r = 0; r < 4; ++r)
                lds[CTXo + w*1024 + (quad*4 + r)*128 + mb*16 + m16] = f2bf(cc[r] * is);
        }
    }

    // ===== fused out-GEMM: ctx^T (8x128) @ Wout_h (128x128) -> partials =====
    bfrag ac[4];
    #pragma unroll
    for (int ks = 0; ks < 4; ++ks)
        ac[ks] = (m16 < 8) ? *(const bfrag*)&lds[CTXo + w*1024 + m16*128 + ks*32 + q8]
                           : bzero();
    const short* Wo = Wout_pt + h * 16384;
    float* pb = part + (size_t)h * 524288 + (size_t)(pg*4 + w) * 8 * 128;
    #pragma unroll 1
    for (int nt = 0; nt < 8; ++nt) {
        f32x4 cc = {0.f,0.f,0.f,0.f};
        #pragma unroll
        for (int ks = 0; ks < 4; ++ks) {
            const bfrag wb = *(const bfrag*)&Wo[(nt*16 + m16)*128 + ks*32 + q8];
            cc = __builtin_amdgcn_mfma_f32_16x16x32_bf16(ac[ks], wb, cc, 0,0,0);
        }
        if (quad < 2) {
            #pragma unroll
            for (int r = 0; r < 4; ++r)
                pb[(quad*4 + r)*128 + nt*16 + m16] = cc[r];
        }
    }
}

// ---------------- reduce8: out[orow][col] = sum_h part[h][rowf][col] --------
__global__ __launch_bounds__(256) void reduce8(
    const float* __restrict__ part, float* __restrict__ out)
{
    const int f = blockIdx.x * 256 + threadIdx.x;   // float4 index, 0..131071
    const int rowf = f >> 5, c4 = f & 31;
    const int pat = rowf >> 3, p = rowf & 7;
    const int bb = pat >> 5, rem = pat & 31;
    const int dd = rem >> 4, hh = (rem >> 2) & 3, ww = rem & 3;
    const int p1 = p >> 2, p2 = (p >> 1) & 1, p3 = p & 1;
    const int orow = bb*256 + ((((dd*2 + p1)*4 + hh)*2 + p2)*4 + ww)*2 + p3;
    const f32x4* p4 = (const f32x4*)part;
    f32x4 s = p4[rowf*32 + c4];
    #pragma unroll
    for (int h = 1; h < 8; ++h)
        s += p4[h*131072 + rowf*32 + c4];
    ((f32x4*)out)[orow*32 + c4] = s;
}

extern "C" void kernel_launch(void* const* d_in, const int* in_sizes, int n_in,
                              void* d_out, int out_size, void* d_ws, size_t ws_size,
                              hipStream_t stream) {
    const float* emb  = (const float*)d_in[0];   // (512, 8, 128)
    const float* Wq   = (const float*)d_in[1];   // (128, 1024)
    const float* Wk   = (const float*)d_in[2];
    const float* Wv   = (const float*)d_in[3];
    const float* Wout = (const float*)d_in[4];   // (1024, 128)
    float* out = (float*)d_out;                  // 524288 floats

    float* part    = (float*)d_ws;                         // 16 MB
    short* Wp      = (short*)((char*)d_ws + 16777216);     // 768 KB
    short* Wout_pt = Wp + 393216;                          // 256 KB

    convertW<<<128, 256, 0, stream>>>(Wq, Wk, Wv, Wout, Wp, Wout_pt);
    attn4<<<1024, 256, 0, stream>>>(emb, Wp, Wout_pt, part);
    reduce8<<<512, 256, 0, stream>>>(part, out);
}

// Round 2
// 109.618 us; speedup vs baseline: 1.0958x; 1.0958x over previous
//
#include <hip/hip_runtime.h>
#include <hip/hip_bf16.h>
#include <math.h>

// Self_Attention_Local R7: fused bf16-MFMA attention, atomic head-reduction.
//   convertW: zeroes out[] (atomic target), Wq/Wk/Wv -> Wp[x][h][i][k] bf16,
//             Wout -> Wout_pt[h][col][i] bf16.
//   attn4:    block = (patch-group of 4, head). R5 structure (Gram stats,
//             40KB LDS, (256,4)) + R6's proven conflict-free P swizzle
//             (quad-key), swizzled VS, exp2 builtin. Epilogue atomically
//             adds the per-head out-GEMM into out[] with the row permute
//             folded in -> no part buffer, no reduce8 kernel.

typedef short bfrag __attribute__((ext_vector_type(8)));   // 8 bf16 = 4 VGPRs
typedef float f32x4 __attribute__((ext_vector_type(4)));

static __device__ __forceinline__ short f2bf(float x) {
    __hip_bfloat16 h = __float2bfloat16(x);
    return __builtin_bit_cast(short, h);
}
static __device__ __forceinline__ bfrag bzero() {
    bfrag z;
    #pragma unroll
    for (int j = 0; j < 8; ++j) z[j] = 0;
    return z;
}

// ---------------- convertW: 128 blocks ----------------
// all blocks: zero a 16KB slice of out (atomic accumulation target)
// blocks 0..95:  (x, h, k-quarter): Wp[x][h][i][k] = Wx[k][i*8+h]
// blocks 96..127:(h, col-quarter):  Wout_pt[h][col][i] = Wout[i*8+h][col]
__global__ __launch_bounds__(256) void convertW(
    const float* __restrict__ Wq, const float* __restrict__ Wk,
    const float* __restrict__ Wv, const float* __restrict__ Wout,
    short* __restrict__ Wp, short* __restrict__ Wout_pt,
    float* __restrict__ out)
{
    __shared__ short lt[128 * 33];          // union: [32][129] or [128][33]
    const int b = blockIdx.x, t = threadIdx.x;

    // zero out: 524288 floats = 131072 float4 = 128 blocks x 1024
    {
        float4* o4 = (float4*)out;
        const int zb = b * 1024 + t;
        #pragma unroll
        for (int k = 0; k < 4; ++k)
            o4[zb + k * 256] = make_float4(0.f, 0.f, 0.f, 0.f);
    }

    if (b < 96) {
        const int x = b >> 5, h = (b >> 2) & 7, k0 = (b & 3) * 32;
        const float* W = (x == 0) ? Wq : (x == 1) ? Wk : Wv;
        #pragma unroll 4
        for (int rr = 0; rr < 16; ++rr) {
            const int k = rr * 2 + (t >> 7);          // 0..31
            const int i = t & 127;
            lt[k * 129 + i] = f2bf(W[(k0 + k) * 1024 + i * 8 + h]);
        }
        __syncthreads();
        short* dst = Wp + (x * 8 + h) * 16384;
        #pragma unroll
        for (int pp = 0; pp < 4; ++pp) {
            const int i  = pp * 32 + (t >> 3);
            const int kk = (t & 7) * 4;
            short4 v;
            v.x = lt[(kk + 0) * 129 + i]; v.y = lt[(kk + 1) * 129 + i];
            v.z = lt[(kk + 2) * 129 + i]; v.w = lt[(kk + 3) * 129 + i];
            *(short4*)&dst[i * 128 + k0 + kk] = v;
        }
    } else {
        const int b2 = b - 96, h = b2 >> 2, c0 = (b2 & 3) * 32;
        #pragma unroll 4
        for (int rr = 0; rr < 16; ++rr) {
            const int i = rr * 8 + (t >> 5);
            const int c = t & 31;
            lt[i * 33 + c] = f2bf(Wout[(i * 8 + h) * 128 + c0 + c]);
        }
        __syncthreads();
        short* dst = Wout_pt + h * 16384;
        #pragma unroll
        for (int pp = 0; pp < 4; ++pp) {
            const int c  = pp * 8 + (t >> 5);
            const int i0 = (t & 31) * 4;
            short4 v;
            v.x = lt[(i0 + 0) * 33 + c]; v.y = lt[(i0 + 1) * 33 + c];
            v.z = lt[(i0 + 2) * 33 + c]; v.w = lt[(i0 + 3) * 33 + c];
            *(short4*)&dst[(c0 + c) * 128 + i0] = v;
        }
    }
}

// ---------------- attn4 ----------------
// LDS zones (shorts): QT[0..4095] Qt[pl][i][p] (persist)
//                     KT[4096..8191] Kt[pl][j][p] (persist)
//                     QN[8192..12287] / KN[12288..16383]: stats, then P bufs
//                     VS[16384..20479]: V swizzled, then CTX
#define QT   0
#define KT   4096
#define QN   8192
#define KN   12288
#define VS   16384
#define CTXo 16384

__global__ __launch_bounds__(256, 4) void attn4(
    const float* __restrict__ emb,      // [4096][128] fp32
    const short* __restrict__ Wp,       // [3][8][128 i][128 k]
    const short* __restrict__ Wout_pt,  // [8][128 col][128 i]
    float* __restrict__ out)            // [4096][128] fp32, atomic target
{
    __shared__ short lds[20480];        // 40 KB
    const int bid = blockIdx.x;         // 0..1023
    const int pg  = bid >> 3;           // patch group of 4
    const int h   = bid & 7;            // head
    const int t   = threadIdx.x;
    const int w    = t >> 6;            // wave 0..3 (owns patch pl = w)
    const int lane = t & 63;
    const int m16  = lane & 15;
    const int quad = lane >> 4;
    const int q8   = quad * 8;

    // ================= QKV: (32x128) @ W_h (128x128) x3 =================
    {
        bfrag a[2][4];
        #pragma unroll
        for (int tm = 0; tm < 2; ++tm)
            #pragma unroll
            for (int ks = 0; ks < 4; ++ks) {
                const float* er = emb + (size_t)(pg*32 + tm*16 + m16) * 128 + ks*32 + q8;
                const float4 x0 = *(const float4*)er;
                const float4 x1 = *(const float4*)(er + 4);
                bfrag f;
                f[0]=f2bf(x0.x); f[1]=f2bf(x0.y); f[2]=f2bf(x0.z); f[3]=f2bf(x0.w);
                f[4]=f2bf(x1.x); f[5]=f2bf(x1.y); f[6]=f2bf(x1.z); f[7]=f2bf(x1.w);
                a[tm][ks] = f;
            }

        #pragma unroll
        for (int tt = 0; tt < 6; ++tt) {
            const int nt = w * 6 + tt;            // 0..23 = {q,k,v} x 8 i-tiles
            const int x  = nt >> 3;
            const int i0 = (nt & 7) * 16;
            const short* Wb = Wp + ((x*8 + h)*128 + i0 + m16) * 128;
            bfrag bb[4];
            #pragma unroll
            for (int ks = 0; ks < 4; ++ks)
                bb[ks] = *(const bfrag*)&Wb[ks*32 + q8];
            f32x4 c0 = {0.f,0.f,0.f,0.f}, c1 = {0.f,0.f,0.f,0.f};
            #pragma unroll
            for (int ks = 0; ks < 4; ++ks) {
                c0 = __builtin_amdgcn_mfma_f32_16x16x32_bf16(a[0][ks], bb[ks], c0, 0,0,0);
                c1 = __builtin_amdgcn_mfma_f32_16x16x32_bf16(a[1][ks], bb[ks], c1, 0,0,0);
            }
            #pragma unroll
            for (int tm = 0; tm < 2; ++tm) {
                const f32x4 cc = tm ? c1 : c0;
                const int mrow0 = tm*16 + quad*4;     // 4 consecutive tokens
                const int pl = mrow0 >> 3;            // local patch
                const int p0 = mrow0 & 7;             // 0 or 4
                const int col = i0 + m16;
                if (x == 0) {
                    short4 v;
                    v.x = f2bf(cc[0]); v.y = f2bf(cc[1]);
                    v.z = f2bf(cc[2]); v.w = f2bf(cc[3]);
                    *(short4*)&lds[QT + pl*1024 + col*8 + p0] = v;   // Qt[i][p]
                    #pragma unroll
                    for (int r = 0; r < 4; ++r)                      // Qn[p][i]
                        lds[QN + pl*1024 + (p0 + r)*128 + col] = f2bf(cc[r]);
                } else if (x == 1) {
                    short4 v;
                    v.x = f2bf(cc[0]); v.y = f2bf(cc[1]);
                    v.z = f2bf(cc[2]); v.w = f2bf(cc[3]);
                    *(short4*)&lds[KT + pl*1024 + col*8 + p0] = v;   // Kt[j][p]
                    #pragma unroll
                    for (int r = 0; r < 4; ++r)                      // Kn[p][j]
                        lds[KN + pl*1024 + (p0 + r)*128 + col] = f2bf(cc[r]);
                } else {
                    // Vs[p][j], column-group swizzled -> conflict-free
                    const int g = (((nt & 7) ^ (((pl & 1) << 1) | (p0 >> 2))) << 4);
                    #pragma unroll
                    for (int r = 0; r < 4; ++r)
                        lds[VS + pl*1024 + (p0 + r)*128 + g + m16] = f2bf(cc[r]);
                }
            }
        }
    }
    __syncthreads();

    // ===== stats via Grams: sum(S)=sQ.sK, sum(S^2)=tr((QQ^T)(KK^T)) =====
    float rs2, nbias;
    {
        bfrag gq[4], gk[4], gs[4], ones;
        #pragma unroll
        for (int j = 0; j < 8; ++j) ones[j] = (short)0x3F80;   // bf16 1.0
        #pragma unroll
        for (int ks = 0; ks < 4; ++ks) {
            gq[ks] = (m16 < 8) ? *(const bfrag*)&lds[QN + w*1024 + m16*128 + ks*32 + q8] : bzero();
            gk[ks] = (m16 < 8) ? *(const bfrag*)&lds[KN + w*1024 + m16*128 + ks*32 + q8] : bzero();
            gs[ks] = (m16 < 8) ? *(const bfrag*)&lds[QN + w*1024 + m16*128 + ks*32 + q8]
                               : *(const bfrag*)&lds[KN + w*1024 + (m16 - 8)*128 + ks*32 + q8];
        }
        f32x4 cg = {0.f,0.f,0.f,0.f}, ch = {0.f,0.f,0.f,0.f}, cs = {0.f,0.f,0.f,0.f};
        #pragma unroll
        for (int ks = 0; ks < 4; ++ks) {
            cg = __builtin_amdgcn_mfma_f32_16x16x32_bf16(gq[ks], gq[ks], cg, 0,0,0);
            ch = __builtin_amdgcn_mfma_f32_16x16x32_bf16(gk[ks], gk[ks], ch, 0,0,0);
            cs = __builtin_amdgcn_mfma_f32_16x16x32_bf16(gs[ks], ones,  cs, 0,0,0);
        }
        float gh = 0.f, sp = 0.f;
        #pragma unroll
        for (int r = 0; r < 4; ++r) {
            gh = fmaf(cg[r], ch[r], gh);
            sp = fmaf(cs[r], __shfl_xor(cs[r], 32), sp);     // sQ[p]*sK[p]
        }
        sp += __shfl_xor(sp, 16);
        #pragma unroll
        for (int off = 1; off <= 32; off <<= 1)
            gh += __shfl_xor(gh, off);
        const float mean = sp * (1.f / 16384.f);
        const float var  = gh * (1.f / 16384.f) - mean * mean;
        rs2   = rsqrtf(var + 1e-5f) * 1.44269504f;           // fold log2(e)
        nbias = -mean * rs2;
    }

    // ===== hoist K-transposed and V fragments (QN/KN/VS die after barrier) ====
    bfrag bs[8], av[4];
    #pragma unroll
    for (int nt = 0; nt < 8; ++nt)
        bs[nt] = (quad == 0) ? *(const bfrag*)&lds[KT + w*1024 + (nt*16 + m16)*8] : bzero();
    #pragma unroll
    for (int ks = 0; ks < 4; ++ks) {
        if (m16 < 8) {
            const int g = (((2*ks + (quad >> 1)) ^ (((w & 1) << 1) | (m16 >> 2))) << 4);
            av[ks] = *(const bfrag*)&lds[VS + w*1024 + m16*128 + g + (quad & 1)*8];
        } else if (m16 == 8) {                 // ones ROW -> C[8][i] = rowsum_i
            bfrag o;
            #pragma unroll
            for (int j = 0; j < 8; ++j) o[j] = (short)0x3F80;
            av[ks] = o;
        } else
            av[ks] = bzero();
    }
    __syncthreads();   // all waves done with QN/KN/VS -> safe to overlay

    // ===== 8 bands of 16 score rows; P conflict-free; manual pipeline ======
    // P addr(i,j) = i*128 + (((j>>4) ^ (i>>2))<<4) + (j&15)
    //   write: i = quad*4+r -> key = quad  (4 quads -> 4 distinct bank octets)
    //   read:  i = m16      -> key = m16>>2
    short* ps = &lds[QN + w*2048];             // 16 x 128 shorts per wave
    f32x4 c[8];
    {
        const bfrag am = (quad == 0) ? *(const bfrag*)&lds[QT + w*1024 + m16*8] : bzero();
        #pragma unroll
        for (int nt = 0; nt < 8; ++nt) {
            f32x4 z = {0.f,0.f,0.f,0.f};
            c[nt] = __builtin_amdgcn_mfma_f32_16x16x32_bf16(am, bs[nt], z, 0,0,0);
        }
    }
    #pragma unroll 1
    for (int mb = 0; mb < 8; ++mb) {
        // exp + swizzled P write (rows quad*4+r, col nt*16+m16)
        #pragma unroll
        for (int nt = 0; nt < 8; ++nt)
            #pragma unroll
            for (int r = 0; r < 4; ++r) {
                const int row = quad*4 + r;
                ps[row*128 + ((nt ^ quad) << 4) + m16] =
                    f2bf(__builtin_amdgcn_exp2f(fmaf(c[nt][r], rs2, nbias)));
            }
        // next band's scores issue between P-write and PV-read (latency cover)
        if (mb < 7) {
            const bfrag am = (quad == 0)
                ? *(const bfrag*)&lds[QT + w*1024 + ((mb+1)*16 + m16)*8] : bzero();
            #pragma unroll
            for (int nt = 0; nt < 8; ++nt) {
                f32x4 z = {0.f,0.f,0.f,0.f};
                c[nt] = __builtin_amdgcn_mfma_f32_16x16x32_bf16(am, bs[nt], z, 0,0,0);
            }
        }
        // PV: C[p][i16] = sum_j V[p][j] * P[i][j]   (B-frag = P rows, b128)
        f32x4 cc = {0.f,0.f,0.f,0.f};
        #pragma unroll
        for (int ks = 0; ks < 4; ++ks) {
            const bfrag bp = *(const bfrag*)
                &ps[m16*128 + (((2*ks + (quad >> 1)) ^ (m16 >> 2)) << 4) + (quad & 1)*8];
            cc = __builtin_amdgcn_mfma_f32_16x16x32_bf16(av[ks], bp, cc, 0,0,0);
        }
        const float s  = __shfl(cc[0], 32 + m16);   // C[8][i] from quad-2 lanes
        const float is = 1.0f / s;
        if (quad < 2) {
            #pragma unroll
            for (int r = 0; r < 4; ++r)
                lds[CTXo + w*1024 + (quad*4 + r)*128 + mb*16 + m16] = f2bf(cc[r] * is);
        }
    }

    // ===== fused out-GEMM: ctx^T (8x128) @ Wout_h -> atomic add into out ====
    bfrag ac[4];
    #pragma unroll
    for (int ks = 0; ks < 4; ++ks)
        ac[ks] = (m16 < 8) ? *(const bfrag*)&lds[CTXo + w*1024 + m16*128 + ks*32 + q8]
                           : bzero();
    const short* Wo = Wout_pt + h * 16384;
    // output row permute: pat = pg*4+w -> (bb,dd,hh,ww); p = quad*4+r -> p1p2p3
    const int pat = pg*4 + w;
    const int bb = pat >> 5, rem = pat & 31;
    const int dd = rem >> 4, hh2 = (rem >> 2) & 3, ww2 = rem & 3;
    #pragma unroll 1
    for (int nt = 0; nt < 8; ++nt) {
        f32x4 cc = {0.f,0.f,0.f,0.f};
        #pragma unroll
        for (int ks = 0; ks < 4; ++ks) {
            const bfrag wb = *(const bfrag*)&Wo[(nt*16 + m16)*128 + ks*32 + q8];
            cc = __builtin_amdgcn_mfma_f32_16x16x32_bf16(ac[ks], wb, cc, 0,0,0);
        }
        if (quad < 2) {
            #pragma unroll
            for (int r = 0; r < 4; ++r) {
                const int orow = bb*256
                    + ((((dd*2 + quad)*4 + hh2)*2 + (r >> 1))*4 + ww2)*2 + (r & 1);
                atomicAdd(&out[(size_t)orow*128 + nt*16 + m16], cc[r]);
            }
        }
    }
}

extern "C" void kernel_launch(void* const* d_in, const int* in_sizes, int n_in,
                              void* d_out, int out_size, void* d_ws, size_t ws_size,
                              hipStream_t stream) {
    const float* emb  = (const float*)d_in[0];   // (512, 8, 128)
    const float* Wq   = (const float*)d_in[1];   // (128, 1024)
    const float* Wk   = (const float*)d_in[2];
    const float* Wv   = (const float*)d_in[3];
    const float* Wout = (const float*)d_in[4];   // (1024, 128)
    float* out = (float*)d_out;                  // 524288 floats

    short* Wp      = (short*)d_ws;               // 768 KB
    short* Wout_pt = Wp + 393216;                // 256 KB

    convertW<<<128, 256, 0, stream>>>(Wq, Wk, Wv, Wout, Wp, Wout_pt, out);
    attn4<<<1024, 256, 0, stream>>>(emb, Wp, Wout_pt, out);
}

// Round 3
// 103.956 us; speedup vs baseline: 1.1555x; 1.0545x over previous
//
#include <hip/hip_runtime.h>
#include <hip/hip_bf16.h>
#include <math.h>

// Self_Attention_Local R8: fused bf16-MFMA attention, atomic head-reduction.
//   convertW: zeroes out[], Wq/Wk/Wv -> Wp bf16, Wout -> Wout_pt bf16.
//   attn4:    block = (patch-group of 4, head). TRANSPOSED scores
//             (mfma(K,Q) -> S^T): each lane holds 4 consecutive j for one i
//             -> P written as short4 b64 (64 writes vs 256 scalar), chunk-XOR
//             swizzled (bank-balanced write AND b128 PV read). Bands iterate
//             over j in 4 slabs of 32; PV accumulates cc[8] across slabs;
//             normalize ONCE at the end (1 shuffle phase vs 8). QN/KN/CTX
//             block-swizzled (key p&3) -> Gram/ac reads 8-way -> 2-way.
//   epilogue: per-head out-GEMM atomically added into out[] (permute folded).

typedef short bfrag __attribute__((ext_vector_type(8)));   // 8 bf16 = 4 VGPRs
typedef float f32x4 __attribute__((ext_vector_type(4)));

static __device__ __forceinline__ short f2bf(float x) {
    __hip_bfloat16 h = __float2bfloat16(x);
    return __builtin_bit_cast(short, h);
}
static __device__ __forceinline__ bfrag bzero() {
    bfrag z;
    #pragma unroll
    for (int j = 0; j < 8; ++j) z[j] = 0;
    return z;
}

// ---------------- convertW: 128 blocks ----------------
__global__ __launch_bounds__(256) void convertW(
    const float* __restrict__ Wq, const float* __restrict__ Wk,
    const float* __restrict__ Wv, const float* __restrict__ Wout,
    short* __restrict__ Wp, short* __restrict__ Wout_pt,
    float* __restrict__ out)
{
    __shared__ short lt[128 * 33];          // union: [32][129] or [128][33]
    const int b = blockIdx.x, t = threadIdx.x;

    // zero out: 524288 floats = 131072 float4 = 128 blocks x 1024
    {
        float4* o4 = (float4*)out;
        const int zb = b * 1024 + t;
        #pragma unroll
        for (int k = 0; k < 4; ++k)
            o4[zb + k * 256] = make_float4(0.f, 0.f, 0.f, 0.f);
    }

    if (b < 96) {
        const int x = b >> 5, h = (b >> 2) & 7, k0 = (b & 3) * 32;
        const float* W = (x == 0) ? Wq : (x == 1) ? Wk : Wv;
        #pragma unroll 4
        for (int rr = 0; rr < 16; ++rr) {
            const int k = rr * 2 + (t >> 7);          // 0..31
            const int i = t & 127;
            lt[k * 129 + i] = f2bf(W[(k0 + k) * 1024 + i * 8 + h]);
        }
        __syncthreads();
        short* dst = Wp + (x * 8 + h) * 16384;
        #pragma unroll
        for (int pp = 0; pp < 4; ++pp) {
            const int i  = pp * 32 + (t >> 3);
            const int kk = (t & 7) * 4;
            short4 v;
            v.x = lt[(kk + 0) * 129 + i]; v.y = lt[(kk + 1) * 129 + i];
            v.z = lt[(kk + 2) * 129 + i]; v.w = lt[(kk + 3) * 129 + i];
            *(short4*)&dst[i * 128 + k0 + kk] = v;
        }
    } else {
        const int b2 = b - 96, h = b2 >> 2, c0 = (b2 & 3) * 32;
        #pragma unroll 4
        for (int rr = 0; rr < 16; ++rr) {
            const int i = rr * 8 + (t >> 5);
            const int c = t & 31;
            lt[i * 33 + c] = f2bf(Wout[(i * 8 + h) * 128 + c0 + c]);
        }
        __syncthreads();
        short* dst = Wout_pt + h * 16384;
        #pragma unroll
        for (int pp = 0; pp < 4; ++pp) {
            const int c  = pp * 8 + (t >> 5);
            const int i0 = (t & 31) * 4;
            short4 v;
            v.x = lt[(i0 + 0) * 33 + c]; v.y = lt[(i0 + 1) * 33 + c];
            v.z = lt[(i0 + 2) * 33 + c]; v.w = lt[(i0 + 3) * 33 + c];
            *(short4*)&dst[(c0 + c) * 128 + i0] = v;
        }
    }
}

// ---------------- attn4 ----------------
// LDS zones (shorts), 40 KB:
//   QT [0..4095]      Qt[pl][i][p]        (dies after bs hoist -> P slab w0)
//   KT [4096..8191]   Kt[pl][j][p]        (live in band loop; then CTX)
//   QN [8192..12287]  Q natural, blk-swz  (dies after Gram -> P slab w1)
//   KN [12288..16383] K natural, blk-swz  (dies after Gram -> P slab w2)
//   VS [16384..20479] V natural, blk-swz  (dies after av hoist -> P slab w3)
// P slab per wave: [128 i][32 j] bf16 = 4096 shorts, chunk-XOR swizzled.
#define QT   0
#define KT   4096
#define QN   8192
#define KN   12288
#define VS   16384
#define CTXK 4096

__global__ __launch_bounds__(256, 4) void attn4(
    const float* __restrict__ emb,      // [4096][128] fp32
    const short* __restrict__ Wp,       // [3][8][128 i][128 k]
    const short* __restrict__ Wout_pt,  // [8][128 col][128 i]
    float* __restrict__ out)            // [4096][128] fp32, atomic target
{
    __shared__ short lds[20480];        // 40 KB
    const int bid = blockIdx.x;         // 0..1023
    const int pg  = bid >> 3;           // patch group of 4
    const int h   = bid & 7;            // head
    const int t   = threadIdx.x;
    const int w    = t >> 6;            // wave 0..3 (owns patch pl = w)
    const int lane = t & 63;
    const int m16  = lane & 15;
    const int quad = lane >> 4;
    const int q8   = quad * 8;

    // ================= QKV: (32x128) @ W_h (128x128) x3 =================
    {
        bfrag a[2][4];
        #pragma unroll
        for (int tm = 0; tm < 2; ++tm)
            #pragma unroll
            for (int ks = 0; ks < 4; ++ks) {
                const float* er = emb + (size_t)(pg*32 + tm*16 + m16) * 128 + ks*32 + q8;
                const float4 x0 = *(const float4*)er;
                const float4 x1 = *(const float4*)(er + 4);
                bfrag f;
                f[0]=f2bf(x0.x); f[1]=f2bf(x0.y); f[2]=f2bf(x0.z); f[3]=f2bf(x0.w);
                f[4]=f2bf(x1.x); f[5]=f2bf(x1.y); f[6]=f2bf(x1.z); f[7]=f2bf(x1.w);
                a[tm][ks] = f;
            }

        #pragma unroll
        for (int tt = 0; tt < 6; ++tt) {
            const int nt = w * 6 + tt;            // 0..23 = {q,k,v} x 8 i-tiles
            const int x  = nt >> 3;
            const int i0 = (nt & 7) * 16;
            const short* Wb = Wp + ((x*8 + h)*128 + i0 + m16) * 128;
            bfrag bb[4];
            #pragma unroll
            for (int ks = 0; ks < 4; ++ks)
                bb[ks] = *(const bfrag*)&Wb[ks*32 + q8];
            f32x4 c0 = {0.f,0.f,0.f,0.f}, c1 = {0.f,0.f,0.f,0.f};
            #pragma unroll
            for (int ks = 0; ks < 4; ++ks) {
                c0 = __builtin_amdgcn_mfma_f32_16x16x32_bf16(a[0][ks], bb[ks], c0, 0,0,0);
                c1 = __builtin_amdgcn_mfma_f32_16x16x32_bf16(a[1][ks], bb[ks], c1, 0,0,0);
            }
            #pragma unroll
            for (int tm = 0; tm < 2; ++tm) {
                const f32x4 cc = tm ? c1 : c0;
                const int mrow0 = tm*16 + quad*4;     // 4 consecutive tokens
                const int pl = mrow0 >> 3;            // local patch
                const int p0 = mrow0 & 7;             // 0 or 4
                const int col = i0 + m16;
                const int cb  = nt & 7;               // column block = i>>4
                if (x == 0) {
                    short4 v;
                    v.x = f2bf(cc[0]); v.y = f2bf(cc[1]);
                    v.z = f2bf(cc[2]); v.w = f2bf(cc[3]);
                    *(short4*)&lds[QT + pl*1024 + col*8 + p0] = v;   // Qt[i][p]
                    #pragma unroll
                    for (int r = 0; r < 4; ++r)       // Qn[p][i], block-swz
                        lds[QN + pl*1024 + (p0 + r)*128
                            + ((cb ^ ((p0 + r) & 3)) << 4) + m16] = f2bf(cc[r]);
                } else if (x == 1) {
                    short4 v;
                    v.x = f2bf(cc[0]); v.y = f2bf(cc[1]);
                    v.z = f2bf(cc[2]); v.w = f2bf(cc[3]);
                    *(short4*)&lds[KT + pl*1024 + col*8 + p0] = v;   // Kt[j][p]
                    #pragma unroll
                    for (int r = 0; r < 4; ++r)       // Kn[p][j], block-swz
                        lds[KN + pl*1024 + (p0 + r)*128
                            + ((cb ^ ((p0 + r) & 3)) << 4) + m16] = f2bf(cc[r]);
                } else {
                    // Vs[p][j], column-group swizzled -> conflict-free
                    const int g = ((cb ^ (((pl & 1) << 1) | (p0 >> 2))) << 4);
                    #pragma unroll
                    for (int r = 0; r < 4; ++r)
                        lds[VS + pl*1024 + (p0 + r)*128 + g + m16] = f2bf(cc[r]);
                }
            }
        }
    }
    __syncthreads();

    // ===== stats via Grams: sum(S)=sQ.sK, sum(S^2)=tr((QQ^T)(KK^T)) =====
    float rs2, nbias;
    {
        bfrag gq[4], gk[4], gs[4], ones;
        #pragma unroll
        for (int j = 0; j < 8; ++j) ones[j] = (short)0x3F80;   // bf16 1.0
        #pragma unroll
        for (int ks = 0; ks < 4; ++ks) {
            const int bswz = (((2*ks + (quad >> 1)) ^ (m16 & 3)) << 4) + (quad & 1)*8;
            gq[ks] = (m16 < 8) ? *(const bfrag*)&lds[QN + w*1024 + m16*128 + bswz] : bzero();
            gk[ks] = (m16 < 8) ? *(const bfrag*)&lds[KN + w*1024 + m16*128 + bswz] : bzero();
            gs[ks] = (m16 < 8) ? *(const bfrag*)&lds[QN + w*1024 + m16*128 + bswz]
                               : *(const bfrag*)&lds[KN + w*1024 + (m16 - 8)*128 + bswz];
        }
        f32x4 cg = {0.f,0.f,0.f,0.f}, ch = {0.f,0.f,0.f,0.f}, cs = {0.f,0.f,0.f,0.f};
        #pragma unroll
        for (int ks = 0; ks < 4; ++ks) {
            cg = __builtin_amdgcn_mfma_f32_16x16x32_bf16(gq[ks], gq[ks], cg, 0,0,0);
            ch = __builtin_amdgcn_mfma_f32_16x16x32_bf16(gk[ks], gk[ks], ch, 0,0,0);
            cs = __builtin_amdgcn_mfma_f32_16x16x32_bf16(gs[ks], ones,  cs, 0,0,0);
        }
        float gh = 0.f, sp = 0.f;
        #pragma unroll
        for (int r = 0; r < 4; ++r) {
            gh = fmaf(cg[r], ch[r], gh);
            sp = fmaf(cs[r], __shfl_xor(cs[r], 32), sp);     // sQ[p]*sK[p]
        }
        sp += __shfl_xor(sp, 16);
        #pragma unroll
        for (int off = 1; off <= 32; off <<= 1)
            gh += __shfl_xor(gh, off);
        const float mean = sp * (1.f / 16384.f);
        const float var  = gh * (1.f / 16384.f) - mean * mean;
        rs2   = rsqrtf(var + 1e-5f) * 1.44269504f;           // fold log2(e)
        nbias = -mean * rs2;
    }

    // ===== hoist Qt B-frags (QT dies) and V A-frags (VS dies) ============
    bfrag bs[8], av[4];
    #pragma unroll
    for (int nt = 0; nt < 8; ++nt)
        bs[nt] = (quad == 0) ? *(const bfrag*)&lds[QT + w*1024 + (nt*16 + m16)*8] : bzero();
    #pragma unroll
    for (int ks = 0; ks < 4; ++ks) {
        if (m16 < 8) {
            const int g = (((2*ks + (quad >> 1)) ^ (((w & 1) << 1) | (m16 >> 2))) << 4);
            av[ks] = *(const bfrag*)&lds[VS + w*1024 + m16*128 + g + (quad & 1)*8];
        } else if (m16 == 8) {                 // ones ROW -> C[8][i] = rowsum_i
            bfrag o;
            #pragma unroll
            for (int j = 0; j < 8; ++j) o[j] = (short)0x3F80;
            av[ks] = o;
        } else
            av[ks] = bzero();
    }
    __syncthreads();   // all waves done with QT/QN/KN/VS -> safe to overlay

    // ===== band loop: 4 j-slabs of 32; S^T scores -> b64 P; PV accumulates =====
    // P slab [128 i][32 j]: addr = i*32 + chunk'*8 + (j&7), chunk' = (j>>3)^(i>>2 & 3)
    short* ps = &lds[(w == 0) ? 0 : (4096 + (w << 12))];   // 4096-short slab
    const int key2 = m16 >> 2;
    const int rowoff = m16 * 32;
    f32x4 cc[8];
    #pragma unroll
    for (int nt = 0; nt < 8; ++nt) cc[nt] = (f32x4){0.f,0.f,0.f,0.f};

    #pragma unroll
    for (int ks = 0; ks < 4; ++ks) {
        #pragma unroll
        for (int bb = 0; bb < 2; ++bb) {
            const int band = ks*2 + bb;
            const bfrag amk = (quad == 0)
                ? *(const bfrag*)&lds[KT + w*1024 + (band*16 + m16)*8] : bzero();
            const int tw = (((bb*2 + (quad >> 1)) ^ key2) << 3) + (quad & 1)*4;
            #pragma unroll
            for (int nt = 0; nt < 8; ++nt) {
                f32x4 z = {0.f,0.f,0.f,0.f};
                const f32x4 s4 = __builtin_amdgcn_mfma_f32_16x16x32_bf16(amk, bs[nt], z, 0,0,0);
                short4 v;
                v.x = f2bf(__builtin_amdgcn_exp2f(fmaf(s4[0], rs2, nbias)));
                v.y = f2bf(__builtin_amdgcn_exp2f(fmaf(s4[1], rs2, nbias)));
                v.z = f2bf(__builtin_amdgcn_exp2f(fmaf(s4[2], rs2, nbias)));
                v.w = f2bf(__builtin_amdgcn_exp2f(fmaf(s4[3], rs2, nbias)));
                *(short4*)&ps[nt*512 + rowoff + tw] = v;
            }
        }
        #pragma unroll
        for (int nt = 0; nt < 8; ++nt) {
            const bfrag bp = *(const bfrag*)&ps[nt*512 + rowoff + ((quad ^ key2) << 3)];
            cc[nt] = __builtin_amdgcn_mfma_f32_16x16x32_bf16(av[ks], bp, cc[nt], 0,0,0);
        }
    }

    // ===== normalize once; ctx -> CTX zone (overlays KT), block-swizzled =====
    #pragma unroll
    for (int nt = 0; nt < 8; ++nt) {
        const float s  = __shfl(cc[nt][0], 32 + m16);   // C[8][i] from quad-2
        const float is = 1.0f / s;
        if (quad < 2) {
            #pragma unroll
            for (int r = 0; r < 4; ++r) {
                const int p = quad*4 + r;
                lds[CTXK + w*1024 + p*128 + ((nt ^ (p & 3)) << 4) + m16] =
                    f2bf(cc[nt][r] * is);
            }
        }
    }

    // ===== fused out-GEMM: ctx^T (8x128) @ Wout_h -> atomic add into out ====
    bfrag ac[4];
    #pragma unroll
    for (int ks = 0; ks < 4; ++ks)
        ac[ks] = (m16 < 8)
            ? *(const bfrag*)&lds[CTXK + w*1024 + m16*128
                  + (((2*ks + (quad >> 1)) ^ (m16 & 3)) << 4) + (quad & 1)*8]
            : bzero();
    const short* Wo = Wout_pt + h * 16384;
    // output row permute: pat = pg*4+w -> (bb,dd,hh,ww); p = quad*4+r -> p1p2p3
    const int pat = pg*4 + w;
    const int bb2 = pat >> 5, rem = pat & 31;
    const int dd = rem >> 4, hh2 = (rem >> 2) & 3, ww2 = rem & 3;
    #pragma unroll 1
    for (int nt = 0; nt < 8; ++nt) {
        f32x4 cc2 = {0.f,0.f,0.f,0.f};
        #pragma unroll
        for (int ks = 0; ks < 4; ++ks) {
            const bfrag wb = *(const bfrag*)&Wo[(nt*16 + m16)*128 + ks*32 + q8];
            cc2 = __builtin_amdgcn_mfma_f32_16x16x32_bf16(ac[ks], wb, cc2, 0,0,0);
        }
        if (quad < 2) {
            #pragma unroll
            for (int r = 0; r < 4; ++r) {
                const int orow = bb2*256
                    + ((((dd*2 + quad)*4 + hh2)*2 + (r >> 1))*4 + ww2)*2 + (r & 1);
                atomicAdd(&out[(size_t)orow*128 + nt*16 + m16], cc2[r]);
            }
        }
    }
}

extern "C" void kernel_launch(void* const* d_in, const int* in_sizes, int n_in,
                              void* d_out, int out_size, void* d_ws, size_t ws_size,
                              hipStream_t stream) {
    const float* emb  = (const float*)d_in[0];   // (512, 8, 128)
    const float* Wq   = (const float*)d_in[1];   // (128, 1024)
    const float* Wk   = (const float*)d_in[2];
    const float* Wv   = (const float*)d_in[3];
    const float* Wout = (const float*)d_in[4];   // (1024, 128)
    float* out = (float*)d_out;                  // 524288 floats

    short* Wp      = (short*)d_ws;               // 768 KB
    short* Wout_pt = Wp + 393216;                // 256 KB

    convertW<<<128, 256, 0, stream>>>(Wq, Wk, Wv, Wout, Wp, Wout_pt, out);
    attn4<<<1024, 256, 0, stream>>>(emb, Wp, Wout_pt, out);
}